// Round 6
// baseline (348.078 us; speedup 1.0000x reference)
//
#include <hip/hip_runtime.h>

// Sparsity_Checker: passthrough-copy + collector histogram (+tiny finalize).
// All four reference outputs derive from the 5-bin histogram of
// collector = sum_t spikes[t] (values 0..T):
//   unique_counts[k]  = hist[k]
//   coll_zero_frac    = hist[0] / total
//   sparsity_ratio    = (total*T - sum_k k*hist[k]) / (total*T)
// Single read of input + single write of output = 411 MB floor (memory-bound).
//
// Session ledger:
//  R0  349.5us  grid 1024 + separate finalize (stats ~95us inferred)
//  R1  766.7us  NT hints + fused finalize w/ fence + grid 2048 -> 513us stats
//  R2  777.5us  fence + grid 2048 (NT reverted)                -> 547us stats
//  R4  418.5us  bisect: grid exonerated (B@2048 ~69us warm); cliff = the
//               per-block agent-scope __threadfence. NEVER fence in the
//               streaming kernel.
//  R5  344.3us  B's config solo: grid 2048, no fence. stats ~90us cold
//               (4.6 TB/s mixed). Preloaded container -> env hypothesis dead.
//  R6  (this)   unroll x2, batched 8-load/8-store issue: longer same-
//               direction HBM bursts to amortize read<->write turnaround.
//               Target stats ~75us. If neutral -> declare roofline ~344.

constexpr int T_STEPS = 4;

__global__ __launch_bounds__(256) void spike_stats_kernel(
    const float4* __restrict__ in, float4* __restrict__ out,
    unsigned int* __restrict__ hist, int nvec)
{
    __shared__ unsigned int lhist[5];
    if (threadIdx.x < 5) lhist[threadIdx.x] = 0u;
    __syncthreads();

    // packed histogram: 5 bins x 12 bits. Per-wave bin max at grid=2048x256,
    // unroll 2: 64 lanes * 8 elems * ceil(6.125/2)=4 iters = 2048 < 4096.
    unsigned long long packed = 0ull;

    const int stride = gridDim.x * blockDim.x;
    int v = blockIdx.x * blockDim.x + threadIdx.x;

    for (; v + stride < nvec; v += 2 * stride) {
        const int w = v + stride;
        // ---- 8-load read burst ----
        float4 a0 = in[0 * nvec + v];
        float4 a1 = in[1 * nvec + v];
        float4 a2 = in[2 * nvec + v];
        float4 a3 = in[3 * nvec + v];
        float4 b0 = in[0 * nvec + w];
        float4 b1 = in[1 * nvec + w];
        float4 b2 = in[2 * nvec + w];
        float4 b3 = in[3 * nvec + w];
        // ---- 8-store write burst ----
        out[0 * nvec + v] = a0;
        out[1 * nvec + v] = a1;
        out[2 * nvec + v] = a2;
        out[3 * nvec + v] = a3;
        out[0 * nvec + w] = b0;
        out[1 * nvec + w] = b1;
        out[2 * nvec + w] = b2;
        out[3 * nvec + w] = b3;
        // elements are exactly 0.0f or 1.0f -> sums are exact small ints
        int cx = (int)(a0.x + a1.x + a2.x + a3.x);
        int cy = (int)(a0.y + a1.y + a2.y + a3.y);
        int cz = (int)(a0.z + a1.z + a2.z + a3.z);
        int cw = (int)(a0.w + a1.w + a2.w + a3.w);
        packed += (1ull << (cx * 12)) + (1ull << (cy * 12))
                + (1ull << (cz * 12)) + (1ull << (cw * 12));
        int dx = (int)(b0.x + b1.x + b2.x + b3.x);
        int dy = (int)(b0.y + b1.y + b2.y + b3.y);
        int dz = (int)(b0.z + b1.z + b2.z + b3.z);
        int dw = (int)(b0.w + b1.w + b2.w + b3.w);
        packed += (1ull << (dx * 12)) + (1ull << (dy * 12))
                + (1ull << (dz * 12)) + (1ull << (dw * 12));
    }
    if (v < nvec) {  // tail: nvec/stride = 6.125 -> 1 extra vec for low tids
        float4 a0 = in[0 * nvec + v];
        float4 a1 = in[1 * nvec + v];
        float4 a2 = in[2 * nvec + v];
        float4 a3 = in[3 * nvec + v];
        out[0 * nvec + v] = a0;
        out[1 * nvec + v] = a1;
        out[2 * nvec + v] = a2;
        out[3 * nvec + v] = a3;
        int cx = (int)(a0.x + a1.x + a2.x + a3.x);
        int cy = (int)(a0.y + a1.y + a2.y + a3.y);
        int cz = (int)(a0.z + a1.z + a2.z + a3.z);
        int cw = (int)(a0.w + a1.w + a2.w + a3.w);
        packed += (1ull << (cx * 12)) + (1ull << (cy * 12))
                + (1ull << (cz * 12)) + (1ull << (cw * 12));
    }

    // wave-64 butterfly reduce of the packed histogram
#pragma unroll
    for (int off = 32; off > 0; off >>= 1)
        packed += __shfl_down(packed, off, 64);

    if ((threadIdx.x & 63) == 0) {
#pragma unroll
        for (int k = 0; k < 5; ++k)
            atomicAdd(&lhist[k], (unsigned int)((packed >> (12 * k)) & 0xFFFull));
    }
    __syncthreads();

    // 5 global atomics per block (2048 blocks) — negligible contention
    if (threadIdx.x < 5)
        atomicAdd(&hist[threadIdx.x], lhist[threadIdx.x]);
}

__global__ void finalize_kernel(const unsigned int* __restrict__ hist,
                                float* __restrict__ tail, double total)
{
    if (threadIdx.x == 0 && blockIdx.x == 0) {
        double spikes_sum = 0.0;
#pragma unroll
        for (int k = 0; k < 5; ++k)
            spikes_sum += (double)k * (double)hist[k];
        double denom = total * (double)T_STEPS;
        tail[0] = (float)((denom - spikes_sum) / denom); // sparsity_ratio
        tail[1] = (float)((double)hist[0] / total);      // coll_zero_frac
#pragma unroll
        for (int k = 0; k < 5; ++k)
            tail[2 + k] = (float)hist[k];                // unique_counts (exact: < 2^24)
    }
}

extern "C" void kernel_launch(void* const* d_in, const int* in_sizes, int n_in,
                              void* d_out, int out_size, void* d_ws, size_t ws_size,
                              hipStream_t stream)
{
    const float* spikes = (const float*)d_in[0];
    float* out = (float*)d_out;

    const long n = (long)in_sizes[0];       // T*B*C*H*W = 51,380,224
    const long per_t = n / T_STEPS;         // 12,845,056 elements per timestep
    const int nvec = (int)(per_t / 4);      // 3,211,264 float4 per timestep

    unsigned int* hist = (unsigned int*)d_ws;
    hipMemsetAsync(d_ws, 0, 8 * sizeof(unsigned int), stream);

    spike_stats_kernel<<<dim3(2048), dim3(256), 0, stream>>>(
        (const float4*)spikes, (float4*)out, hist, nvec);

    finalize_kernel<<<dim3(1), dim3(64), 0, stream>>>(hist, out + n, (double)per_t);
}

// Round 7
// 347.324 us; speedup vs baseline: 1.0022x; 1.0022x over previous
//
#include <hip/hip_runtime.h>

// Sparsity_Checker: passthrough-copy + collector histogram (+tiny finalize).
// All four reference outputs derive from the 5-bin histogram of
// collector = sum_t spikes[t] (values 0..T):
//   unique_counts[k]  = hist[k]
//   coll_zero_frac    = hist[0] / total
//   sparsity_ratio    = (total*T - sum_k k*hist[k]) / (total*T)
// Single read of input + single write of output = 411 MB floor (memory-bound).
//
// Session ledger (final):
//  R0  349.5us  grid 1024 + separate finalize (stats ~95us inferred)
//  R1  766.7us  NT hints + fused finalize w/ fence + grid 2048 -> 513us stats
//  R2  777.5us  fence + grid 2048 (NT reverted)                -> 547us stats
//  R4  418.5us  bisect: grid exonerated (B@2048 ~69us warm); cliff = the
//               per-block agent-scope __threadfence. NEVER fence inside a
//               streaming kernel on gfx950.
//  R5  344.3us  BEST. grid 2048, no fence, separate finalize. stats ~90us.
//  R6  348.1us  unroll x2 / 8-load-8-store bursts: neutral (source-level
//               burst ordering doesn't reach the DRAM controller).
//  R7  (this)   revert to R5 exactly. Remaining gap (~25us of 344) is the
//               4+4-stream structure forced by the [T,...] layout (the
//               histogram of sum_t needs all 4 t-slices at one index) —
//               no further source-level lever identified. Roofline.

constexpr int T_STEPS = 4;

__global__ __launch_bounds__(256) void spike_stats_kernel(
    const float4* __restrict__ in, float4* __restrict__ out,
    unsigned int* __restrict__ hist, int nvec)
{
    __shared__ unsigned int lhist[5];
    if (threadIdx.x < 5) lhist[threadIdx.x] = 0u;
    __syncthreads();

    // packed histogram: 5 bins x 12 bits. Per-wave bin max at grid=2048x256:
    // 64 lanes * 4 elems * ceil(3211264/524288)=7 iters = 1792 < 4096.
    unsigned long long packed = 0ull;

    const int stride = gridDim.x * blockDim.x;
    for (int v = blockIdx.x * blockDim.x + threadIdx.x; v < nvec; v += stride) {
        float4 a0 = in[0 * nvec + v];
        float4 a1 = in[1 * nvec + v];
        float4 a2 = in[2 * nvec + v];
        float4 a3 = in[3 * nvec + v];
        out[0 * nvec + v] = a0;
        out[1 * nvec + v] = a1;
        out[2 * nvec + v] = a2;
        out[3 * nvec + v] = a3;
        // elements are exactly 0.0f or 1.0f -> sums are exact small ints
        int cx = (int)(a0.x + a1.x + a2.x + a3.x);
        int cy = (int)(a0.y + a1.y + a2.y + a3.y);
        int cz = (int)(a0.z + a1.z + a2.z + a3.z);
        int cw = (int)(a0.w + a1.w + a2.w + a3.w);
        packed += (1ull << (cx * 12)) + (1ull << (cy * 12))
                + (1ull << (cz * 12)) + (1ull << (cw * 12));
    }

    // wave-64 butterfly reduce of the packed histogram
#pragma unroll
    for (int off = 32; off > 0; off >>= 1)
        packed += __shfl_down(packed, off, 64);

    if ((threadIdx.x & 63) == 0) {
#pragma unroll
        for (int k = 0; k < 5; ++k)
            atomicAdd(&lhist[k], (unsigned int)((packed >> (12 * k)) & 0xFFFull));
    }
    __syncthreads();

    // 5 global atomics per block (2048 blocks) — negligible contention
    if (threadIdx.x < 5)
        atomicAdd(&hist[threadIdx.x], lhist[threadIdx.x]);
}

__global__ void finalize_kernel(const unsigned int* __restrict__ hist,
                                float* __restrict__ tail, double total)
{
    if (threadIdx.x == 0 && blockIdx.x == 0) {
        double spikes_sum = 0.0;
#pragma unroll
        for (int k = 0; k < 5; ++k)
            spikes_sum += (double)k * (double)hist[k];
        double denom = total * (double)T_STEPS;
        tail[0] = (float)((denom - spikes_sum) / denom); // sparsity_ratio
        tail[1] = (float)((double)hist[0] / total);      // coll_zero_frac
#pragma unroll
        for (int k = 0; k < 5; ++k)
            tail[2 + k] = (float)hist[k];                // unique_counts (exact: < 2^24)
    }
}

extern "C" void kernel_launch(void* const* d_in, const int* in_sizes, int n_in,
                              void* d_out, int out_size, void* d_ws, size_t ws_size,
                              hipStream_t stream)
{
    const float* spikes = (const float*)d_in[0];
    float* out = (float*)d_out;

    const long n = (long)in_sizes[0];       // T*B*C*H*W = 51,380,224
    const long per_t = n / T_STEPS;         // 12,845,056 elements per timestep
    const int nvec = (int)(per_t / 4);      // 3,211,264 float4 per timestep

    unsigned int* hist = (unsigned int*)d_ws;
    hipMemsetAsync(d_ws, 0, 8 * sizeof(unsigned int), stream);

    spike_stats_kernel<<<dim3(2048), dim3(256), 0, stream>>>(
        (const float4*)spikes, (float4*)out, hist, nvec);

    finalize_kernel<<<dim3(1), dim3(64), 0, stream>>>(hist, out + n, (double)per_t);
}